// Round 1
// baseline (1510.057 us; speedup 1.0000x reference)
//
#include <hip/hip_runtime.h>
#include <hip/hip_bf16.h>
#include <math.h>

// GPT-OSS MoE: rmsnorm -> gate top4 -> mxfp4 MLP1 -> swiglu -> mxfp4 MLP2 -> combine
// Sizes fixed per reference: E=32, H=1024, I=1024, N=1024 tokens, top-4.

#define NE 32
#define HD 1024
#define ID 1024
#define NTOK 1024
#define R1 2048      // 2*I rows of mlp1
#define G1 32        // H/32 groups per row (mlp1)
#define G2 32        // I/32 groups per row (mlp2)
#define GBY 16       // packed bytes (int32 each) per group

// workspace layout (bytes)
#define T_OFF    0            // t: [NTOK][HD] f32 = 4 MB
#define A_OFF    4194304      // a: [4096][ID] f32 = 16 MB
#define CNT_OFF  20971520     // counts: int[NE]
#define OFF_OFF  20971776     // offsets: int[NE+1]
#define TOKL_OFF 20972032     // tok_list: int[NE*NTOK]
#define WTL_OFF  21103104     // wt_list: float[NE*NTOK]
#define TIDX_OFF 21234176     // top_idx: int[NTOK*4]
#define TWT_OFF  21250560     // top_wt: float[NTOK*4]

__device__ __forceinline__ void dec2(unsigned byte, float sc, float& flo, float& fhi) {
    // fp4 e2m1 nibble -> 2*|value| via magic LUT, sign from bit3/bit7, scale sc = 2^(s-127)/2
    const unsigned MAGIC = 0xC8643210u;
    float lo = (float)((MAGIC >> ((byte & 7u) << 2)) & 15u);
    float hi = (float)((MAGIC >> (((byte >> 4) & 7u) << 2)) & 15u);
    lo = __uint_as_float(__float_as_uint(lo) | ((byte & 8u) << 28));
    hi = __uint_as_float(__float_as_uint(hi) | ((byte & 128u) << 24));
    flo = lo * sc;
    fhi = hi * sc;
}

__global__ __launch_bounds__(256) void k_gate(
    const float* __restrict__ x, const float* __restrict__ norm_w,
    const float* __restrict__ gate_w, const float* __restrict__ gate_b,
    float* __restrict__ t, float* __restrict__ out,
    int* __restrict__ top_idx, float* __restrict__ top_wt)
{
    int n = blockIdx.x;
    int tid = threadIdx.x;
    __shared__ float tl[HD];
    __shared__ float red[4];
    __shared__ float logits[NE];

    const float4* xv = (const float4*)(x + (size_t)n * HD);
    float4 v = xv[tid];
    float ss = v.x * v.x + v.y * v.y + v.z * v.z + v.w * v.w;
    #pragma unroll
    for (int off = 32; off; off >>= 1) ss += __shfl_down(ss, off);
    if ((tid & 63) == 0) red[tid >> 6] = ss;
    __syncthreads();
    float tot = red[0] + red[1] + red[2] + red[3];
    float rms = rsqrtf(tot * (1.0f / HD) + 1e-5f);

    float4 w = ((const float4*)norm_w)[tid];
    float4 tv;
    tv.x = v.x * rms * w.x; tv.y = v.y * rms * w.y;
    tv.z = v.z * rms * w.z; tv.w = v.w * rms * w.w;
    ((float4*)(t + (size_t)n * HD))[tid] = tv;
    ((float4*)(out + (size_t)n * HD))[tid] = v;   // out = x (residual base)
    ((float4*)tl)[tid] = tv;
    __syncthreads();

    int wv = tid >> 6, lane = tid & 63;
    for (int j = 0; j < 8; j++) {
        int e = wv * 8 + j;
        const float* gw = gate_w + (size_t)e * HD;
        float p = 0.f;
        #pragma unroll
        for (int q = 0; q < 16; q++) { int kk = lane + q * 64; p += tl[kk] * gw[kk]; }
        #pragma unroll
        for (int off = 32; off; off >>= 1) p += __shfl_down(p, off);
        if (lane == 0) logits[e] = p + gate_b[e];
    }
    __syncthreads();

    if (tid == 0) {
        float vals[4]; int idx[4];
        unsigned used = 0;
        #pragma unroll
        for (int kk = 0; kk < 4; kk++) {
            float best = -1e30f; int bi = 0;
            for (int e2 = 0; e2 < NE; e2++) {
                if (used & (1u << e2)) continue;
                if (logits[e2] > best) { best = logits[e2]; bi = e2; }
            }
            used |= 1u << bi; vals[kk] = best; idx[kk] = bi;
        }
        float m = vals[0], s = 0.f, ex[4];
        #pragma unroll
        for (int kk = 0; kk < 4; kk++) { ex[kk] = __expf(vals[kk] - m); s += ex[kk]; }
        float inv = 1.0f / s;
        #pragma unroll
        for (int kk = 0; kk < 4; kk++) {
            top_idx[n * 4 + kk] = idx[kk];
            top_wt[n * 4 + kk] = ex[kk] * inv;
        }
    }
}

__global__ void k_build(const int* __restrict__ top_idx, const float* __restrict__ top_wt,
                        int* __restrict__ counts, int* __restrict__ tok_list,
                        float* __restrict__ wt_list)
{
    int i = blockIdx.x * 256 + threadIdx.x;
    if (i >= NTOK * 4) return;
    int n = i >> 2;
    int e = top_idx[i];
    int slot = atomicAdd(counts + e, 1);
    tok_list[e * NTOK + slot] = n;
    wt_list[e * NTOK + slot] = top_wt[i];
}

__global__ void k_prefix(const int* __restrict__ counts, int* __restrict__ offsets)
{
    if (threadIdx.x == 0) {
        int s = 0;
        for (int e = 0; e < NE; e++) { offsets[e] = s; s += counts[e]; }
        offsets[NE] = s;
    }
}

// MLP1 + swiglu. Block: expert e x 32 rows (of 2048). Threads: (row 0..31) x (tokgrp 0..7).
__global__ __launch_bounds__(256) void k_mlp1(
    const float* __restrict__ t, const int* __restrict__ blocks,
    const int* __restrict__ scales, const float* __restrict__ bias,
    const int* __restrict__ counts, const int* __restrict__ offsets,
    const int* __restrict__ tok_list, float* __restrict__ a)
{
    int e = blockIdx.y;
    int cnt = counts[e];
    if (cnt == 0) return;
    int r0 = blockIdx.x * 32;
    int tid = threadIdx.x;
    int rl = tid & 31;
    int tg = tid >> 5;
    int row = r0 + rl;
    int base = offsets[e];
    int lid = e * NTOK;

    __shared__ float tl[64][128];   // token chunk x k-tile (32 KB)
    __shared__ float hl[32][65];    // rows x tokens, padded (8.1 KB)

    float b_row = bias[e * R1 + row];

    for (int c0 = 0; c0 < cnt; c0 += 64) {
        int nt = min(64, cnt - c0);
        float acc[8] = {0, 0, 0, 0, 0, 0, 0, 0};

        #pragma unroll 1
        for (int kt = 0; kt < 8; kt++) {
            int k0 = kt * 128;
            __syncthreads();
            for (int idx = tid; idx < nt * 128; idx += 256) {
                int tok = idx >> 7; int kk = idx & 127;
                int n = tok_list[lid + c0 + tok];
                tl[tok][kk] = t[(size_t)n * HD + k0 + kk];
            }
            __syncthreads();

            const int* wb = blocks + ((size_t)(e * R1 + row) * G1 + kt * 4) * GBY;
            const int* sb = scales + (size_t)(e * R1 + row) * G1 + kt * 4;
            #pragma unroll
            for (int g = 0; g < 4; g++) {
                int s = sb[g];
                float sc = __uint_as_float((unsigned)(s - 1) << 23); // 2^(s-127) * 0.5
                const int4* wp = (const int4*)(wb + g * GBY);
                #pragma unroll
                for (int q = 0; q < 4; q++) {
                    int4 w4 = wp[q];
                    unsigned bs0 = (unsigned)w4.x, bs1 = (unsigned)w4.y;
                    unsigned bs2 = (unsigned)w4.z, bs3 = (unsigned)w4.w;
                    unsigned bb[4] = {bs0, bs1, bs2, bs3};
                    #pragma unroll
                    for (int b = 0; b < 4; b++) {
                        float flo, fhi;
                        dec2(bb[b], sc, flo, fhi);
                        int kk = g * 32 + (q * 4 + b) * 2;
                        #pragma unroll
                        for (int j = 0; j < 8; j++) {
                            acc[j] = fmaf(flo, tl[tg * 8 + j][kk], acc[j]);
                            acc[j] = fmaf(fhi, tl[tg * 8 + j][kk + 1], acc[j]);
                        }
                    }
                }
            }
        }

        __syncthreads();
        #pragma unroll
        for (int j = 0; j < 8; j++) hl[rl][tg * 8 + j] = acc[j] + b_row;
        __syncthreads();

        // swiglu: 16 pairs x 64 tokens
        for (int q = tid; q < 16 * 64; q += 256) {
            int tok = q >> 4; int p = q & 15;
            if (tok < nt) {
                float hg = fminf(hl[2 * p][tok], 7.0f);
                float hx = hl[2 * p + 1][tok];
                hx = fminf(fmaxf(hx, -7.0f), 7.0f);
                float sig = 1.0f / (1.0f + __expf(-1.702f * hg));
                float av = hg * sig * (hx + 1.0f);
                a[(size_t)(base + c0 + tok) * ID + (r0 >> 1) + p] = av;
            }
        }
        __syncthreads();
    }
}

// MLP2 + weighted combine. Block: expert e x 32 rows (of H).
__global__ __launch_bounds__(256) void k_mlp2(
    const float* __restrict__ a, const int* __restrict__ blocks,
    const int* __restrict__ scales, const float* __restrict__ bias,
    const int* __restrict__ counts, const int* __restrict__ offsets,
    const int* __restrict__ tok_list, const float* __restrict__ wt_list,
    float* __restrict__ out)
{
    int e = blockIdx.y;
    int cnt = counts[e];
    if (cnt == 0) return;
    int r0 = blockIdx.x * 32;
    int tid = threadIdx.x;
    int rl = tid & 31;
    int tg = tid >> 5;
    int row = r0 + rl;
    int base = offsets[e];

    __shared__ float al[64][128];

    float b_row = bias[e * HD + row];

    for (int c0 = 0; c0 < cnt; c0 += 64) {
        int nt = min(64, cnt - c0);
        float acc[8] = {0, 0, 0, 0, 0, 0, 0, 0};

        #pragma unroll 1
        for (int kt = 0; kt < 8; kt++) {
            int k0 = kt * 128;
            __syncthreads();
            for (int idx = tid; idx < nt * 128; idx += 256) {
                int tok = idx >> 7; int kk = idx & 127;
                al[tok][kk] = a[(size_t)(base + c0 + tok) * ID + k0 + kk];
            }
            __syncthreads();

            const int* wb = blocks + ((size_t)(e * HD + row) * G2 + kt * 4) * GBY;
            const int* sb = scales + (size_t)(e * HD + row) * G2 + kt * 4;
            #pragma unroll
            for (int g = 0; g < 4; g++) {
                int s = sb[g];
                float sc = __uint_as_float((unsigned)(s - 1) << 23);
                const int4* wp = (const int4*)(wb + g * GBY);
                #pragma unroll
                for (int q = 0; q < 4; q++) {
                    int4 w4 = wp[q];
                    unsigned bb[4] = {(unsigned)w4.x, (unsigned)w4.y, (unsigned)w4.z, (unsigned)w4.w};
                    #pragma unroll
                    for (int b = 0; b < 4; b++) {
                        float flo, fhi;
                        dec2(bb[b], sc, flo, fhi);
                        int kk = g * 32 + (q * 4 + b) * 2;
                        #pragma unroll
                        for (int j = 0; j < 8; j++) {
                            acc[j] = fmaf(flo, al[tg * 8 + j][kk], acc[j]);
                            acc[j] = fmaf(fhi, al[tg * 8 + j][kk + 1], acc[j]);
                        }
                    }
                }
            }
        }

        #pragma unroll
        for (int j = 0; j < 8; j++) {
            int tok = tg * 8 + j;
            if (c0 + tok < cnt) {
                int n = tok_list[e * NTOK + c0 + tok];
                float wgt = wt_list[e * NTOK + c0 + tok];
                atomicAdd(out + (size_t)n * HD + row, wgt * (acc[j] + b_row));
            }
        }
        __syncthreads();
    }
}

extern "C" void kernel_launch(void* const* d_in, const int* in_sizes, int n_in,
                              void* d_out, int out_size, void* d_ws, size_t ws_size,
                              hipStream_t stream)
{
    const float* x          = (const float*)d_in[0];
    const float* norm_w     = (const float*)d_in[1];
    const float* gate_w     = (const float*)d_in[2];
    const float* gate_b     = (const float*)d_in[3];
    const float* mlp1_bias  = (const float*)d_in[4];
    const float* mlp2_bias  = (const float*)d_in[5];
    const int*   mlp1_blocks = (const int*)d_in[6];
    const int*   mlp1_scales = (const int*)d_in[7];
    const int*   mlp2_blocks = (const int*)d_in[8];
    const int*   mlp2_scales = (const int*)d_in[9];
    float* out = (float*)d_out;

    char* ws = (char*)d_ws;
    float* t       = (float*)(ws + T_OFF);
    float* a       = (float*)(ws + A_OFF);
    int*   counts  = (int*)(ws + CNT_OFF);
    int*   offsets = (int*)(ws + OFF_OFF);
    int*   tok_list = (int*)(ws + TOKL_OFF);
    float* wt_list  = (float*)(ws + WTL_OFF);
    int*   top_idx  = (int*)(ws + TIDX_OFF);
    float* top_wt   = (float*)(ws + TWT_OFF);

    hipMemsetAsync(counts, 0, NE * sizeof(int), stream);
    k_gate<<<NTOK, 256, 0, stream>>>(x, norm_w, gate_w, gate_b, t, out, top_idx, top_wt);
    k_build<<<(NTOK * 4 + 255) / 256, 256, 0, stream>>>(top_idx, top_wt, counts, tok_list, wt_list);
    k_prefix<<<1, 64, 0, stream>>>(counts, offsets);
    k_mlp1<<<dim3(64, NE), 256, 0, stream>>>(t, mlp1_blocks, mlp1_scales, mlp1_bias,
                                             counts, offsets, tok_list, a);
    k_mlp2<<<dim3(32, NE), 256, 0, stream>>>(a, mlp2_blocks, mlp2_scales, mlp2_bias,
                                             counts, offsets, tok_list, wt_list, out);
}

// Round 2
// 153.846 us; speedup vs baseline: 9.8154x; 9.8154x over previous
//
#include <hip/hip_runtime.h>
#include <hip/hip_bf16.h>
#include <math.h>

// GPT-OSS MoE: rmsnorm -> gate top4 -> mxfp4 MLP1 (MFMA) -> swiglu -> mxfp4 MLP2 (MFMA) -> combine
// E=32, H=1024, I=1024, N=1024 tokens, top-4.

#define NE 32
#define HD 1024
#define ID 1024
#define NTOK 1024
#define R1 2048
#define TCH 160          // token chunk (5 tiles of 32) -- covers max expert load in 1 pass

typedef __attribute__((ext_vector_type(8)))  short bf16x8;
typedef __attribute__((ext_vector_type(16))) float f32x16;

// ---- workspace layout (bytes) ----
#define TB_OFF   0            // t_bf16 [1024][1024] bf16 = 2 MB
#define A_OFF    2097152      // a      [4096][1024] bf16 = 8 MB
#define YB_OFF   10485760     // yb     [4096][1024] bf16 = 8 MB
#define CNT_OFF  18874368     // counts int[32]
#define OFFS_OFF 18874624     // offsets int[33]
#define TOKL_OFF 18874880     // tok_list int[32*1024]
#define TIDX_OFF 19005952     // top_idx int[1024*4]
#define TWT_OFF  19022336     // top_wt  f32[1024*4]
#define POS_OFF  19038720     // pos_of  int[1024*4]

__device__ __forceinline__ unsigned f2bf(float f) {
    unsigned u = __float_as_uint(f);
    return (u + 0x7FFFu + ((u >> 16) & 1u)) >> 16;   // RNE
}
__device__ __forceinline__ float bf2f(unsigned u) {
    return __uint_as_float(u << 16);
}

// decode 8 fp4 elems (4 int32s, each holding one byte = 2 nibbles) -> 4 u32 (8 bf16),
// with E8M0 scale folded in as packed exponent add. "zero" encoded as 2^-87 -> ~2^-96 after scale.
__device__ __forceinline__ void dec8(int4 wv, unsigned dd, uint4& o) {
    unsigned u = __builtin_amdgcn_perm((unsigned)wv.y, (unsigned)wv.x, 0x00000400u); // {x0,y0,-,-}
    unsigned v = __builtin_amdgcn_perm((unsigned)wv.w, (unsigned)wv.z, 0x04000000u); // {-,-,z0,w0}
    unsigned packed = __builtin_amdgcn_perm(v, u, 0x07060100u);                      // {x0,y0,z0,w0}
    unsigned selE = packed & 0x07070707u;
    unsigned sE   = packed & 0x08080808u;
    unsigned ph   = packed >> 4;
    unsigned selO = ph & 0x07070707u;
    unsigned sO   = ph & 0x08080808u;
    const unsigned PH_hi = 0x40404040u, PH_lo = 0x3F3F3F14u;  // bf16 high bytes for |fp4| 4..7 / 0..3 (0 -> exp 40)
    const unsigned PL_hi = 0xC0804000u, PL_lo = 0xC0800000u;  // bf16 low bytes
    unsigned hbE = __builtin_amdgcn_perm(PH_hi, PH_lo, selE) | (sE << 4);
    unsigned lbE = __builtin_amdgcn_perm(PL_hi, PL_lo, selE);
    unsigned hbO = __builtin_amdgcn_perm(PH_hi, PH_lo, selO) | (sO << 4);
    unsigned lbO = __builtin_amdgcn_perm(PL_hi, PL_lo, selO);
    unsigned mE0 = __builtin_amdgcn_perm(hbE, lbE, 0x05010400u); // bf16(e0)|bf16(e2)<<16
    unsigned mE1 = __builtin_amdgcn_perm(hbE, lbE, 0x07030602u); // e4,e6
    unsigned mO0 = __builtin_amdgcn_perm(hbO, lbO, 0x05010400u); // e1,e3
    unsigned mO1 = __builtin_amdgcn_perm(hbO, lbO, 0x07030602u); // e5,e7
    unsigned r0 = __builtin_amdgcn_perm(mO0, mE0, 0x05040100u);  // {e0,e1}
    unsigned r1 = __builtin_amdgcn_perm(mO0, mE0, 0x07060302u);  // {e2,e3}
    unsigned r2 = __builtin_amdgcn_perm(mO1, mE1, 0x05040100u);  // {e4,e5}
    unsigned r3 = __builtin_amdgcn_perm(mO1, mE1, 0x07060302u);  // {e6,e7}
    unsigned o0, o1, o2, o3;
    asm("v_pk_add_u16 %0, %1, %2" : "=v"(o0) : "v"(r0), "v"(dd));
    asm("v_pk_add_u16 %0, %1, %2" : "=v"(o1) : "v"(r1), "v"(dd));
    asm("v_pk_add_u16 %0, %1, %2" : "=v"(o2) : "v"(r2), "v"(dd));
    asm("v_pk_add_u16 %0, %1, %2" : "=v"(o3) : "v"(r3), "v"(dd));
    o.x = o0; o.y = o1; o.z = o2; o.w = o3;
}

__global__ __launch_bounds__(256) void k_gate(
    const float* __restrict__ x, const float* __restrict__ norm_w,
    const float* __restrict__ gate_w, const float* __restrict__ gate_b,
    ushort* __restrict__ t_bf16, int* __restrict__ top_idx, float* __restrict__ top_wt)
{
    int n = blockIdx.x;
    int tid = threadIdx.x;
    __shared__ float tl[HD];
    __shared__ float red[4];
    __shared__ float logits[NE];

    const float4* xv = (const float4*)(x + (size_t)n * HD);
    float4 v = xv[tid];
    float ss = v.x * v.x + v.y * v.y + v.z * v.z + v.w * v.w;
    #pragma unroll
    for (int off = 32; off; off >>= 1) ss += __shfl_down(ss, off);
    if ((tid & 63) == 0) red[tid >> 6] = ss;
    __syncthreads();
    float tot = red[0] + red[1] + red[2] + red[3];
    float rms = rsqrtf(tot * (1.0f / HD) + 1e-5f);

    float4 w = ((const float4*)norm_w)[tid];
    float4 tv;
    tv.x = v.x * rms * w.x; tv.y = v.y * rms * w.y;
    tv.z = v.z * rms * w.z; tv.w = v.w * rms * w.w;
    ushort4 tb;
    tb.x = (ushort)f2bf(tv.x); tb.y = (ushort)f2bf(tv.y);
    tb.z = (ushort)f2bf(tv.z); tb.w = (ushort)f2bf(tv.w);
    ((ushort4*)(t_bf16 + (size_t)n * HD))[tid] = tb;
    ((float4*)tl)[tid] = tv;
    __syncthreads();

    int wv = tid >> 6, lane = tid & 63;
    for (int j = 0; j < 8; j++) {
        int e = wv * 8 + j;
        const float* gw = gate_w + (size_t)e * HD;
        float p = 0.f;
        #pragma unroll
        for (int q = 0; q < 16; q++) { int kk = lane + q * 64; p += tl[kk] * gw[kk]; }
        #pragma unroll
        for (int off = 32; off; off >>= 1) p += __shfl_down(p, off);
        if (lane == 0) logits[e] = p + gate_b[e];
    }
    __syncthreads();

    if (tid == 0) {
        float vals[4]; int idx[4];
        unsigned used = 0;
        #pragma unroll
        for (int kk = 0; kk < 4; kk++) {
            float best = -1e30f; int bi = 0;
            for (int e2 = 0; e2 < NE; e2++) {
                if (used & (1u << e2)) continue;
                if (logits[e2] > best) { best = logits[e2]; bi = e2; }
            }
            used |= 1u << bi; vals[kk] = best; idx[kk] = bi;
        }
        float m = vals[0], s = 0.f, ex[4];
        #pragma unroll
        for (int kk = 0; kk < 4; kk++) { ex[kk] = __expf(vals[kk] - m); s += ex[kk]; }
        float inv = 1.0f / s;
        #pragma unroll
        for (int kk = 0; kk < 4; kk++) {
            top_idx[n * 4 + kk] = idx[kk];
            top_wt[n * 4 + kk] = ex[kk] * inv;
        }
    }
}

__global__ void k_build(const int* __restrict__ top_idx, int* __restrict__ counts,
                        int* __restrict__ tok_list, int* __restrict__ pos_of)
{
    int i = blockIdx.x * 256 + threadIdx.x;
    if (i >= NTOK * 4) return;
    int n = i >> 2;
    int e = top_idx[i];
    int slot = atomicAdd(counts + e, 1);
    tok_list[e * NTOK + slot] = n;
    pos_of[i] = slot;
}

__global__ void k_prefix(const int* __restrict__ counts, int* __restrict__ offsets)
{
    if (threadIdx.x == 0) {
        int s = 0;
        for (int e = 0; e < NE; e++) { offsets[e] = s; s += counts[e]; }
        offsets[NE] = s;
    }
}

// MLP1 (MFMA) + swiglu. Block: expert x 128 weight rows. 4 waves x 32 rows.
// A = tokens (M, tiles of 32), B = weights (N=32 per wave). D[m=token][n=row].
__global__ __launch_bounds__(256) void k_mlp1(
    const ushort* __restrict__ t_bf16, const int* __restrict__ blocks,
    const int* __restrict__ scales, const float* __restrict__ bias,
    const int* __restrict__ counts, const int* __restrict__ offsets,
    const int* __restrict__ tok_list, ushort* __restrict__ a)
{
    int e = blockIdx.y;
    int cnt = counts[e];
    if (cnt == 0) return;
    int r0 = blockIdx.x * 128;
    int tid = threadIdx.x;
    int w = tid >> 6, l = tid & 63;
    int base = offsets[e];

    __shared__ ushort tl[TCH][72];   // tokens x k-tile (padded)
    __shared__ ushort wl[128][72];   // weight rows x k-tile (decoded bf16)
    __shared__ int tlist[TCH];

    int lrow = r0 + w * 32 + (l & 31);
    float b_lane = bias[e * R1 + lrow];
    int srow = tid >> 1, shalf = tid & 1;     // staging: 1 row-half (32 elems) per thread

    for (int c0 = 0; c0 < cnt; c0 += TCH) {
        int nt = min(TCH, cnt - c0);
        __syncthreads();
        if (tid < TCH) tlist[tid] = tok_list[e * NTOK + c0 + min(tid, nt - 1)];
        f32x16 acc[5] = {};

        #pragma unroll 1
        for (int k0 = 0; k0 < HD; k0 += 64) {
            __syncthreads();
            // stage tokens: TCH rows x 8 segs of 16B
            for (int idx = tid; idx < TCH * 8; idx += 256) {
                int tok = idx >> 3, seg = idx & 7;
                *(uint4*)&tl[tok][seg * 8] =
                    *(const uint4*)(t_bf16 + (size_t)tlist[tok] * HD + k0 + seg * 8);
            }
            // stage weights (decode fp4 -> bf16 with scale folded)
            {
                int g = (k0 >> 5) + shalf;
                size_t rbase = (size_t)(e * R1 + r0 + srow) * 32 + g;
                int s = scales[rbase];
                unsigned dd16 = (unsigned)((s - 127) << 7) & 0xFFFFu;
                unsigned dd = dd16 | (dd16 << 16);
                const int4* wp = (const int4*)(blocks + rbase * 16);
                ushort* dst = &wl[srow][shalf * 32];
                #pragma unroll
                for (int q = 0; q < 4; q++) {
                    uint4 ov;
                    dec8(wp[q], dd, ov);
                    *(uint4*)(dst + q * 8) = ov;
                }
            }
            __syncthreads();
            #pragma unroll
            for (int ks = 0; ks < 4; ks++) {
                bf16x8 wf = *(const bf16x8*)&wl[w * 32 + (l & 31)][ks * 16 + (l >> 5) * 8];
                #pragma unroll
                for (int mt = 0; mt < 5; mt++) {
                    bf16x8 af = *(const bf16x8*)&tl[mt * 32 + (l & 31)][ks * 16 + (l >> 5) * 8];
                    acc[mt] = __builtin_amdgcn_mfma_f32_32x32x16_bf16(af, wf, acc[mt], 0, 0, 0);
                }
            }
        }

        // epilogue: bias + swiglu (glu/lin = adjacent lanes), write a[tok][i] bf16
        int p0 = (r0 + w * 32) >> 1;
        int pcol = p0 + ((l & 31) >> 1);
        #pragma unroll
        for (int mt = 0; mt < 5; mt++) {
            #pragma unroll
            for (int r = 0; r < 16; r++) {
                float h = acc[mt][r] + b_lane;
                float other = __shfl_xor(h, 1, 64);
                int m = (r & 3) + 8 * (r >> 2) + 4 * (l >> 5);
                int tokg = c0 + mt * 32 + m;
                if (!(l & 1) && tokg < cnt) {
                    float hg = fminf(h, 7.0f);
                    float hx = fminf(fmaxf(other, -7.0f), 7.0f);
                    float sig = 1.0f / (1.0f + __expf(-1.702f * hg));
                    float av = hg * sig * (hx + 1.0f);
                    a[(size_t)(base + tokg) * ID + pcol] = (ushort)f2bf(av);
                }
            }
        }
    }
}

// MLP2 (MFMA). Block: expert x 128 H-rows. Writes yb[slot][h] bf16 (bias added).
__global__ __launch_bounds__(256) void k_mlp2(
    const ushort* __restrict__ a, const int* __restrict__ blocks,
    const int* __restrict__ scales, const float* __restrict__ bias,
    const int* __restrict__ counts, const int* __restrict__ offsets,
    ushort* __restrict__ yb)
{
    int e = blockIdx.y;
    int cnt = counts[e];
    if (cnt == 0) return;
    int r0 = blockIdx.x * 128;
    int tid = threadIdx.x;
    int w = tid >> 6, l = tid & 63;
    int base = offsets[e];

    __shared__ ushort tl[TCH][72];
    __shared__ ushort wl[128][72];

    int lrow = r0 + w * 32 + (l & 31);
    float b_lane = bias[e * HD + lrow];
    int srow = tid >> 1, shalf = tid & 1;

    for (int c0 = 0; c0 < cnt; c0 += TCH) {
        int nt = min(TCH, cnt - c0);
        f32x16 acc[5] = {};

        #pragma unroll 1
        for (int k0 = 0; k0 < ID; k0 += 64) {
            __syncthreads();
            for (int idx = tid; idx < TCH * 8; idx += 256) {
                int tok = idx >> 3, seg = idx & 7;
                int slot = base + c0 + min(tok, nt - 1);
                *(uint4*)&tl[tok][seg * 8] =
                    *(const uint4*)(a + (size_t)slot * ID + k0 + seg * 8);
            }
            {
                int g = (k0 >> 5) + shalf;
                size_t rbase = (size_t)(e * HD + r0 + srow) * 32 + g;
                int s = scales[rbase];
                unsigned dd16 = (unsigned)((s - 127) << 7) & 0xFFFFu;
                unsigned dd = dd16 | (dd16 << 16);
                const int4* wp = (const int4*)(blocks + rbase * 16);
                ushort* dst = &wl[srow][shalf * 32];
                #pragma unroll
                for (int q = 0; q < 4; q++) {
                    uint4 ov;
                    dec8(wp[q], dd, ov);
                    *(uint4*)(dst + q * 8) = ov;
                }
            }
            __syncthreads();
            #pragma unroll
            for (int ks = 0; ks < 4; ks++) {
                bf16x8 wf = *(const bf16x8*)&wl[w * 32 + (l & 31)][ks * 16 + (l >> 5) * 8];
                #pragma unroll
                for (int mt = 0; mt < 5; mt++) {
                    bf16x8 af = *(const bf16x8*)&tl[mt * 32 + (l & 31)][ks * 16 + (l >> 5) * 8];
                    acc[mt] = __builtin_amdgcn_mfma_f32_32x32x16_bf16(af, wf, acc[mt], 0, 0, 0);
                }
            }
        }

        int hcol = r0 + w * 32 + (l & 31);
        #pragma unroll
        for (int mt = 0; mt < 5; mt++) {
            #pragma unroll
            for (int r = 0; r < 16; r++) {
                int m = (r & 3) + 8 * (r >> 2) + 4 * (l >> 5);
                int tokg = c0 + mt * 32 + m;
                if (tokg < cnt) {
                    float y = acc[mt][r] + b_lane;
                    yb[(size_t)(base + tokg) * HD + hcol] = (ushort)f2bf(y);
                }
            }
        }
    }
}

__global__ __launch_bounds__(256) void k_combine(
    const float* __restrict__ x, const ushort* __restrict__ yb,
    const int* __restrict__ top_idx, const float* __restrict__ top_wt,
    const int* __restrict__ pos_of, const int* __restrict__ offsets,
    float* __restrict__ out)
{
    int n = blockIdx.x, tid = threadIdx.x;
    float4 xv = ((const float4*)(x + (size_t)n * HD))[tid];
    float r0 = xv.x, r1 = xv.y, r2 = xv.z, r3 = xv.w;
    #pragma unroll
    for (int k = 0; k < 4; k++) {
        int e = top_idx[n * 4 + k];
        float wt = top_wt[n * 4 + k];
        int slot = offsets[e] + pos_of[n * 4 + k];
        ushort4 yv = ((const ushort4*)(yb + (size_t)slot * HD))[tid];
        r0 += wt * bf2f(yv.x); r1 += wt * bf2f(yv.y);
        r2 += wt * bf2f(yv.z); r3 += wt * bf2f(yv.w);
    }
    float4 ov; ov.x = r0; ov.y = r1; ov.z = r2; ov.w = r3;
    ((float4*)(out + (size_t)n * HD))[tid] = ov;
}

extern "C" void kernel_launch(void* const* d_in, const int* in_sizes, int n_in,
                              void* d_out, int out_size, void* d_ws, size_t ws_size,
                              hipStream_t stream)
{
    const float* x           = (const float*)d_in[0];
    const float* norm_w      = (const float*)d_in[1];
    const float* gate_w      = (const float*)d_in[2];
    const float* gate_b      = (const float*)d_in[3];
    const float* mlp1_bias   = (const float*)d_in[4];
    const float* mlp2_bias   = (const float*)d_in[5];
    const int*   mlp1_blocks = (const int*)d_in[6];
    const int*   mlp1_scales = (const int*)d_in[7];
    const int*   mlp2_blocks = (const int*)d_in[8];
    const int*   mlp2_scales = (const int*)d_in[9];
    float* out = (float*)d_out;

    char* ws = (char*)d_ws;
    ushort* t_bf16  = (ushort*)(ws + TB_OFF);
    ushort* a       = (ushort*)(ws + A_OFF);
    ushort* yb      = (ushort*)(ws + YB_OFF);
    int*   counts   = (int*)(ws + CNT_OFF);
    int*   offsets  = (int*)(ws + OFFS_OFF);
    int*   tok_list = (int*)(ws + TOKL_OFF);
    int*   top_idx  = (int*)(ws + TIDX_OFF);
    float* top_wt   = (float*)(ws + TWT_OFF);
    int*   pos_of   = (int*)(ws + POS_OFF);

    hipMemsetAsync(counts, 0, NE * sizeof(int), stream);
    k_gate<<<NTOK, 256, 0, stream>>>(x, norm_w, gate_w, gate_b, t_bf16, top_idx, top_wt);
    k_build<<<(NTOK * 4 + 255) / 256, 256, 0, stream>>>(top_idx, counts, tok_list, pos_of);
    k_prefix<<<1, 64, 0, stream>>>(counts, offsets);
    k_mlp1<<<dim3(16, NE), 256, 0, stream>>>(t_bf16, mlp1_blocks, mlp1_scales, mlp1_bias,
                                             counts, offsets, tok_list, a);
    k_mlp2<<<dim3(8, NE), 256, 0, stream>>>(a, mlp2_blocks, mlp2_scales, mlp2_bias,
                                            counts, offsets, yb);
    k_combine<<<NTOK, 256, 0, stream>>>(x, yb, top_idx, top_wt, pos_of, offsets, out);
}